// Round 2
// baseline (779.344 us; speedup 1.0000x reference)
//
#include <hip/hip_runtime.h>
#include <stdint.h>

#define BATCH 64
#define NQ 300
#define NCLS 80
#define NCH 84            // 4 + 80
#define KTOP 150
#define NTOT (NQ * NCH)   // 25200
#define KDIM 1200
#define HW 640

// ---------------- Kernel 1: 32x32 average pool (exact int sum) --------------
// x: (64,3,640,640) int32  ->  At: (1200, 64) double   (A transposed)
// flat k = c_new*400 + ph*20 + pw, where c_new = 2 - c_in  (BGR flip)
__global__ __launch_bounds__(256) void pool_kernel(const int* __restrict__ x,
                                                   double* __restrict__ At) {
  int wave = threadIdx.x >> 6;
  int lane = threadIdx.x & 63;
  int cell = blockIdx.x * 4 + wave;            // 0 .. 76799
  int b   = cell / 1200;
  int rem = cell - b * 1200;
  int cin = rem / 400;
  int pp  = rem - cin * 400;                   // ph*20 + pw
  int ph = pp / 20, pw = pp - ph * 20;
  const int* base = x + (((b * 3 + cin) * HW) + ph * 32) * HW + pw * 32;
  int r  = lane >> 1;                          // 0..31 (row in block)
  int c0 = (lane & 1) * 16;                    // 0 or 16 (col in block)
  const int4* p = (const int4*)(base + r * HW + c0);
  int4 v0 = p[0], v1 = p[1], v2 = p[2], v3 = p[3];
  int s = v0.x + v0.y + v0.z + v0.w + v1.x + v1.y + v1.z + v1.w
        + v2.x + v2.y + v2.z + v2.w + v3.x + v3.y + v3.z + v3.w;
  #pragma unroll
  for (int off = 32; off > 0; off >>= 1) s += __shfl_down(s, off);
  if (lane == 0) {
    int kout = (2 - cin) * 400 + pp;
    At[kout * 64 + b] = (double)s * (1.0 / 261120.0);  // / (255*1024), near-exact
  }
}

// ---------------- Kernel 2: fp64-accumulate GEMM, scalar-broadcast A --------
// At: (1200,64) double   W: (1200,25200) float   Y: (64, 25200) double
// Each wave: 16 batch rows (wave-uniform -> A reads are scalar loads),
// each lane: one output column. Inner loop: 1 coalesced W load + 16 v_fma_f64.
// Row-split (gridDim.y=2) for occupancy: 788 blocks of 2 waves.
__global__ __launch_bounds__(128) void gemm_kernel(const double* __restrict__ At,
                                                   const float* __restrict__ W,
                                                   double* __restrict__ Y) {
  int wave = threadIdx.x >> 6;
  int lane = threadIdx.x & 63;
  int row0 = __builtin_amdgcn_readfirstlane(blockIdx.y * 32 + wave * 16);
  int n  = blockIdx.x * 64 + lane;
  int nl = n < NTOT ? n : NTOT - 1;            // clamp (no divergent load)
  const double* Ap = At + row0;                // Ap[k*64 + i]
  const float*  Wp = W + nl;
  double acc[16];
  #pragma unroll
  for (int i = 0; i < 16; ++i) acc[i] = 0.0;
  #pragma unroll 2
  for (int k = 0; k < KDIM; ++k) {
    double w = (double)Wp[(size_t)k * NTOT];
    #pragma unroll
    for (int i = 0; i < 16; ++i)
      acc[i] = fma(Ap[(size_t)k * 64 + i], w, acc[i]);
  }
  if (n < NTOT) {
    #pragma unroll
    for (int i = 0; i < 16; ++i)
      Y[(size_t)(row0 + i) * NTOT + n] = acc[i];
  }
}

// ---------------- Kernel 3: argmax over classes + stable top-150 ------------
// One block per batch. Strict total order (score desc, q asc) -> exact rank
// selection, O(300^2) comparisons per batch. Matches jax.lax.top_k stability
// (ties -> lower index first) and numpy argmax (first occurrence).
__global__ __launch_bounds__(256) void topk_kernel(const double* __restrict__ Y,
                                                   float* __restrict__ out) {
  __shared__ double sc[NQ];
  __shared__ int    cid[NQ];
  int b = blockIdx.x;
  int t = threadIdx.x;
  const double* y = Y + (size_t)b * NTOT;
  for (int q = t; q < NQ; q += 256) {
    const double* row = y + q * NCH + 4;
    double best = row[0]; int bi = 0;
    #pragma unroll 4
    for (int j = 1; j < NCLS; ++j) {
      double v = row[j];
      if (v > best) { best = v; bi = j; }      // strict > keeps first occurrence
    }
    sc[q] = best; cid[q] = bi;
  }
  __syncthreads();
  for (int q = t; q < NQ; q += 256) {
    double s = sc[q];
    int rank = 0;
    for (int j = 0; j < NQ; ++j) {
      double sj = sc[j];
      rank += (sj > s) || (sj == s && j < q);
    }
    if (rank < KTOP) {
      const double* row = y + q * NCH;
      float* o = out + ((size_t)b * KTOP + rank) * 6;
      o[0] = (float)row[0];
      o[1] = (float)row[1];
      o[2] = (float)row[2];
      o[3] = (float)row[3];
      o[4] = (float)s;
      o[5] = (float)cid[q];
    }
  }
}

extern "C" void kernel_launch(void* const* d_in, const int* in_sizes, int n_in,
                              void* d_out, int out_size, void* d_ws, size_t ws_size,
                              hipStream_t stream) {
  const int*   x = (const int*)d_in[0];
  const float* W = (const float*)d_in[1];
  double* At = (double*)d_ws;                                // 1200*64*8 = 614400 B
  double* Y  = (double*)((char*)d_ws + 614400);              // 64*25200*8 = 12.9 MB
  pool_kernel<<<dim3(19200), dim3(256), 0, stream>>>(x, At);
  gemm_kernel<<<dim3(394, 2), dim3(128), 0, stream>>>(At, W, Y);
  topk_kernel<<<dim3(64), dim3(256), 0, stream>>>(Y, (float*)d_out);
}

// Round 3
// 628.700 us; speedup vs baseline: 1.2396x; 1.2396x over previous
//
#include <hip/hip_runtime.h>
#include <stdint.h>

#define BATCH 64
#define NQ 300
#define NCLS 80
#define NCH 84            // 4 + 80
#define KTOP 150
#define NTOT (NQ * NCH)   // 25200
#define KDIM 1200
#define HW 640

// ws layout (bytes):
//   At : [0, 614400)                 1200*64 double
//   Y  : [614400, 13516800)          64*25200 double
//   sc : [13516800, 13670400)        64*300 double
//   cid: [13670400, 13747200)        64*300 int
#define WS_Y   614400
#define WS_SC  13516800
#define WS_CID 13670400

// ---------------- Kernel 1: 32x32 average pool (exact int sum) --------------
// x: (64,3,640,640) int32  ->  At: (1200, 64) double   (A transposed)
// flat k = c_new*400 + ph*20 + pw, where c_new = 2 - c_in  (BGR flip)
__global__ __launch_bounds__(256) void pool_kernel(const int* __restrict__ x,
                                                   double* __restrict__ At) {
  int wave = threadIdx.x >> 6;
  int lane = threadIdx.x & 63;
  int cell = blockIdx.x * 4 + wave;            // 0 .. 76799
  int b   = cell / 1200;
  int rem = cell - b * 1200;
  int cin = rem / 400;
  int pp  = rem - cin * 400;                   // ph*20 + pw
  int ph = pp / 20, pw = pp - ph * 20;
  const int* base = x + (((b * 3 + cin) * HW) + ph * 32) * HW + pw * 32;
  int r  = lane >> 1;                          // 0..31 (row in block)
  int c0 = (lane & 1) * 16;                    // 0 or 16 (col in block)
  const int4* p = (const int4*)(base + r * HW + c0);
  int4 v0 = p[0], v1 = p[1], v2 = p[2], v3 = p[3];
  int s = v0.x + v0.y + v0.z + v0.w + v1.x + v1.y + v1.z + v1.w
        + v2.x + v2.y + v2.z + v2.w + v3.x + v3.y + v3.z + v3.w;
  #pragma unroll
  for (int off = 32; off > 0; off >>= 1) s += __shfl_down(s, off);
  if (lane == 0) {
    int kout = (2 - cin) * 400 + pp;
    At[kout * 64 + b] = (double)s * (1.0 / 261120.0);  // / (255*1024)
  }
}

// ---------------- Kernel 2: fp64-accumulate GEMM, scalar-broadcast A --------
// At: (1200,64) double   W: (1200,25200) float   Y: (64,25200) double
// Row-split: blockIdx.y picks rows [y*32, y*32+32); each of the 4 waves takes
// 8 rows (wave-uniform -> A reads are scalar loads); each lane one column.
// k unrolled by 8 with all 8 W loads issued before the FMA block -> 8
// outstanding vmem loads per wave. Full K=1200 sequential fp64 chain per
// output (bit-identical to the R2 passing kernel).
__global__ __launch_bounds__(256) void gemm_kernel(const double* __restrict__ At,
                                                   const float* __restrict__ W,
                                                   double* __restrict__ Y) {
  int wave = threadIdx.x >> 6;
  int lane = threadIdx.x & 63;
  int row0 = __builtin_amdgcn_readfirstlane((int)(blockIdx.y * 32 + wave * 8));
  int n  = blockIdx.x * 64 + lane;
  int nl = n < NTOT ? n : NTOT - 1;            // clamp (no divergent load)
  const double* Ap = At + row0;                // Ap[k*64 + i]
  const float*  Wp = W + nl;
  double acc[8];
  #pragma unroll
  for (int i = 0; i < 8; ++i) acc[i] = 0.0;
  for (int k0 = 0; k0 < KDIM; k0 += 8) {
    float w[8];
    #pragma unroll
    for (int u = 0; u < 8; ++u) w[u] = Wp[(size_t)(k0 + u) * NTOT];
    #pragma unroll
    for (int u = 0; u < 8; ++u) {
      double wd = (double)w[u];
      #pragma unroll
      for (int i = 0; i < 8; ++i)
        acc[i] = fma(Ap[(size_t)(k0 + u) * 64 + i], wd, acc[i]);
    }
  }
  if (n < NTOT) {
    #pragma unroll
    for (int i = 0; i < 8; ++i)
      Y[(size_t)(row0 + i) * NTOT + n] = acc[i];
  }
}

// ---------------- Kernel 3a: per-query argmax over 80 classes ---------------
// One wave per (b,q). Lane l holds class l (and class 64+l for l<16);
// shuffle max-reduce with tie -> smaller class index (numpy argmax order).
__global__ __launch_bounds__(256) void argmax_kernel(const double* __restrict__ Y,
                                                     double* __restrict__ sc,
                                                     int* __restrict__ cid) {
  int wave = threadIdx.x >> 6;
  int lane = threadIdx.x & 63;
  int task = blockIdx.x * 4 + wave;            // 0 .. 19199
  int b = task / NQ;
  int q = task - b * NQ;
  const double* y = Y + (size_t)b * NTOT + q * NCH;
  double v1 = y[4 + lane];
  int    c1 = lane;
  double best = v1; int cls = c1;
  if (lane < 16) {
    double v2 = y[68 + lane];
    if (v2 > best) { best = v2; cls = 64 + lane; }   // strict > : lower idx wins ties
  }
  #pragma unroll
  for (int off = 32; off > 0; off >>= 1) {
    double ob = __shfl_down(best, off);
    int    oc = __shfl_down(cls, off);
    if (ob > best || (ob == best && oc < cls)) { best = ob; cls = oc; }
  }
  if (lane == 0) { sc[task] = best; cid[task] = cls; }
}

// ---------------- Kernel 3b: stable top-150 by rank selection ---------------
// One block per batch; scores in LDS; exact rank under (score desc, q asc);
// only the 150 winners touch global Y for their boxes.
__global__ __launch_bounds__(256) void select_kernel(const double* __restrict__ Y,
                                                     const double* __restrict__ sc,
                                                     const int* __restrict__ cid,
                                                     float* __restrict__ out) {
  __shared__ double ssc[NQ];
  __shared__ int    scid[NQ];
  int b = blockIdx.x;
  int t = threadIdx.x;
  for (int q = t; q < NQ; q += 256) {
    ssc[q]  = sc[b * NQ + q];
    scid[q] = cid[b * NQ + q];
  }
  __syncthreads();
  for (int q = t; q < NQ; q += 256) {
    double s = ssc[q];
    int rank = 0;
    for (int j = 0; j < NQ; ++j) {
      double sj = ssc[j];
      rank += (sj > s) || (sj == s && j < q);
    }
    if (rank < KTOP) {
      const double* row = Y + (size_t)b * NTOT + q * NCH;
      float* o = out + ((size_t)b * KTOP + rank) * 6;
      o[0] = (float)row[0];
      o[1] = (float)row[1];
      o[2] = (float)row[2];
      o[3] = (float)row[3];
      o[4] = (float)s;
      o[5] = (float)scid[q];
    }
  }
}

extern "C" void kernel_launch(void* const* d_in, const int* in_sizes, int n_in,
                              void* d_out, int out_size, void* d_ws, size_t ws_size,
                              hipStream_t stream) {
  const int*   x = (const int*)d_in[0];
  const float* W = (const float*)d_in[1];
  double* At  = (double*)d_ws;
  double* Y   = (double*)((char*)d_ws + WS_Y);
  double* sc  = (double*)((char*)d_ws + WS_SC);
  int*    cid = (int*)((char*)d_ws + WS_CID);
  pool_kernel<<<dim3(19200), dim3(256), 0, stream>>>(x, At);
  gemm_kernel<<<dim3(394, 2), dim3(256), 0, stream>>>(At, W, Y);
  argmax_kernel<<<dim3(4800), dim3(256), 0, stream>>>(Y, sc, cid);
  select_kernel<<<dim3(64), dim3(256), 0, stream>>>(Y, sc, cid, (float*)d_out);
}

// Round 4
// 614.579 us; speedup vs baseline: 1.2681x; 1.0230x over previous
//
#include <hip/hip_runtime.h>
#include <stdint.h>

#define BATCH 64
#define NQ 300
#define NCLS 80
#define NCH 84            // 4 + 80
#define KTOP 150
#define NTOT (NQ * NCH)   // 25200
#define KDIM 1200
#define HW 640

// ws layout (bytes):
//   At : [0, 614400)                 1200*64 double
//   Y  : [614400, 13516800)          64*25200 double
//   sc : [13516800, 13670400)        64*300 double
//   cid: [13670400, 13747200)        64*300 int
#define WS_Y   614400
#define WS_SC  13516800
#define WS_CID 13670400

// ---------------- Kernel 1: 32x32 average pool (exact int sum) --------------
// x: (64,3,640,640) int32  ->  At: (1200, 64) double   (A transposed)
// flat k = c_new*400 + ph*20 + pw, where c_new = 2 - c_in  (BGR flip)
__global__ __launch_bounds__(256) void pool_kernel(const int* __restrict__ x,
                                                   double* __restrict__ At) {
  int wave = threadIdx.x >> 6;
  int lane = threadIdx.x & 63;
  int cell = blockIdx.x * 4 + wave;            // 0 .. 76799
  int b   = cell / 1200;
  int rem = cell - b * 1200;
  int cin = rem / 400;
  int pp  = rem - cin * 400;                   // ph*20 + pw
  int ph = pp / 20, pw = pp - ph * 20;
  const int* base = x + (((b * 3 + cin) * HW) + ph * 32) * HW + pw * 32;
  int r  = lane >> 1;                          // 0..31 (row in block)
  int c0 = (lane & 1) * 16;                    // 0 or 16 (col in block)
  const int4* p = (const int4*)(base + r * HW + c0);
  int4 v0 = p[0], v1 = p[1], v2 = p[2], v3 = p[3];
  int s = v0.x + v0.y + v0.z + v0.w + v1.x + v1.y + v1.z + v1.w
        + v2.x + v2.y + v2.z + v2.w + v3.x + v3.y + v3.z + v3.w;
  #pragma unroll
  for (int off = 32; off > 0; off >>= 1) s += __shfl_down(s, off);
  if (lane == 0) {
    int kout = (2 - cin) * 400 + pp;
    At[kout * 64 + b] = (double)s * (1.0 / 261120.0);  // / (255*1024)
  }
}

// ---------------- Kernel 2: fp64 GEMM, scalar A + register double-buffer ----
// At: (1200,64) double   W: (1200,25200) float   Y: (64,25200) double
// Each of 4 waves: 8 batch rows (wave-uniform -> A reads are scalar loads),
// each lane one output column. W values for k-step t+1 are prefetched into a
// second register set before the FMA block of step t, so the vmcnt wait lands
// a full ~256-cycle FMA block after issue (x3 waves/SIMD resident).
// k-chain per output is ascending, sequential fp64 fma -> bit-identical to
// the R2/R3 passing kernels.
__global__ __launch_bounds__(256) void gemm_kernel(const double* __restrict__ At,
                                                   const float* __restrict__ W,
                                                   double* __restrict__ Y) {
  int wave = threadIdx.x >> 6;
  int lane = threadIdx.x & 63;
  int row0 = __builtin_amdgcn_readfirstlane((int)(blockIdx.y * 32 + wave * 8));
  int n  = blockIdx.x * 64 + lane;
  int nl = n < NTOT ? n : NTOT - 1;            // clamp (no divergent load)
  const double* Ap = At + row0;                // Ap[k*64 + i]
  const float*  Wp = W + nl;
  double acc[8];
  #pragma unroll
  for (int i = 0; i < 8; ++i) acc[i] = 0.0;
  float w[8];
  #pragma unroll
  for (int u = 0; u < 8; ++u) w[u] = Wp[(size_t)u * NTOT];
  #pragma unroll 1
  for (int k0 = 0; k0 < KDIM; k0 += 8) {
    int kn = (k0 + 8 == KDIM) ? 0 : k0 + 8;    // last prefetch wraps (unused)
    float wn[8];
    #pragma unroll
    for (int u = 0; u < 8; ++u) wn[u] = Wp[(size_t)(kn + u) * NTOT];
    #pragma unroll
    for (int u = 0; u < 8; ++u) {
      double wd = (double)w[u];
      #pragma unroll
      for (int i = 0; i < 8; ++i)
        acc[i] = fma(Ap[(size_t)(k0 + u) * 64 + i], wd, acc[i]);
    }
    #pragma unroll
    for (int u = 0; u < 8; ++u) w[u] = wn[u];
  }
  if (n < NTOT) {
    #pragma unroll
    for (int i = 0; i < 8; ++i)
      Y[(size_t)(row0 + i) * NTOT + n] = acc[i];
  }
}

// ---------------- Kernel 3a: per-query argmax over 80 classes ---------------
// One wave per (b,q). Lane l holds class l (and class 64+l for l<16);
// shuffle max-reduce with tie -> smaller class index (numpy argmax order).
__global__ __launch_bounds__(256) void argmax_kernel(const double* __restrict__ Y,
                                                     double* __restrict__ sc,
                                                     int* __restrict__ cid) {
  int wave = threadIdx.x >> 6;
  int lane = threadIdx.x & 63;
  int task = blockIdx.x * 4 + wave;            // 0 .. 19199
  int b = task / NQ;
  int q = task - b * NQ;
  const double* y = Y + (size_t)b * NTOT + q * NCH;
  double best = y[4 + lane];
  int    cls  = lane;
  if (lane < 16) {
    double v2 = y[68 + lane];
    if (v2 > best) { best = v2; cls = 64 + lane; }   // strict > : lower idx wins ties
  }
  #pragma unroll
  for (int off = 32; off > 0; off >>= 1) {
    double ob = __shfl_down(best, off);
    int    oc = __shfl_down(cls, off);
    if (ob > best || (ob == best && oc < cls)) { best = ob; cls = oc; }
  }
  if (lane == 0) { sc[task] = best; cid[task] = cls; }
}

// ---------------- Kernel 3b: stable top-150 by rank selection ---------------
// One block per batch; scores in LDS; exact rank under (score desc, q asc);
// only the 150 winners touch global Y for their boxes.
__global__ __launch_bounds__(256) void select_kernel(const double* __restrict__ Y,
                                                     const double* __restrict__ sc,
                                                     const int* __restrict__ cid,
                                                     float* __restrict__ out) {
  __shared__ double ssc[NQ];
  __shared__ int    scid[NQ];
  int b = blockIdx.x;
  int t = threadIdx.x;
  for (int q = t; q < NQ; q += 256) {
    ssc[q]  = sc[b * NQ + q];
    scid[q] = cid[b * NQ + q];
  }
  __syncthreads();
  for (int q = t; q < NQ; q += 256) {
    double s = ssc[q];
    int rank = 0;
    for (int j = 0; j < NQ; ++j) {
      double sj = ssc[j];
      rank += (sj > s) || (sj == s && j < q);
    }
    if (rank < KTOP) {
      const double* row = Y + (size_t)b * NTOT + q * NCH;
      float* o = out + ((size_t)b * KTOP + rank) * 6;
      o[0] = (float)row[0];
      o[1] = (float)row[1];
      o[2] = (float)row[2];
      o[3] = (float)row[3];
      o[4] = (float)s;
      o[5] = (float)scid[q];
    }
  }
}

extern "C" void kernel_launch(void* const* d_in, const int* in_sizes, int n_in,
                              void* d_out, int out_size, void* d_ws, size_t ws_size,
                              hipStream_t stream) {
  const int*   x = (const int*)d_in[0];
  const float* W = (const float*)d_in[1];
  double* At  = (double*)d_ws;
  double* Y   = (double*)((char*)d_ws + WS_Y);
  double* sc  = (double*)((char*)d_ws + WS_SC);
  int*    cid = (int*)((char*)d_ws + WS_CID);
  pool_kernel<<<dim3(19200), dim3(256), 0, stream>>>(x, At);
  gemm_kernel<<<dim3(394, 2), dim3(256), 0, stream>>>(At, W, Y);
  argmax_kernel<<<dim3(4800), dim3(256), 0, stream>>>(Y, sc, cid);
  select_kernel<<<dim3(64), dim3(256), 0, stream>>>(Y, sc, cid, (float*)d_out);
}

// Round 5
// 591.284 us; speedup vs baseline: 1.3181x; 1.0394x over previous
//
#include <hip/hip_runtime.h>
#include <stdint.h>

#define BATCH 64
#define NQ 300
#define NCLS 80
#define NCH 84            // 4 + 80
#define KTOP 150
#define NTOT (NQ * NCH)   // 25200
#define KDIM 1200
#define KCH  600          // K chunk (2 chunks)
#define HW 640

// ws layout (bytes):
//   At : [0, 614400)                    1200*64 double
//   Y  : [614400, 26419200)             2 * 64*25200 double (K-chunk partials)
//   sc : [26419200, 26572800)           64*300 double
//   cid: [26572800, 26649600)           64*300 int
#define WS_Y   614400
#define WS_SC  26419200
#define WS_CID 26572800

// ---------------- Kernel 1: 32x32 average pool (exact int sum) --------------
// x: (64,3,640,640) int32  ->  At: (1200, 64) double   (A transposed)
// flat k = c_new*400 + ph*20 + pw, where c_new = 2 - c_in  (BGR flip)
__global__ __launch_bounds__(256) void pool_kernel(const int* __restrict__ x,
                                                   double* __restrict__ At) {
  int wave = threadIdx.x >> 6;
  int lane = threadIdx.x & 63;
  int cell = blockIdx.x * 4 + wave;            // 0 .. 76799
  int b   = cell / 1200;
  int rem = cell - b * 1200;
  int cin = rem / 400;
  int pp  = rem - cin * 400;                   // ph*20 + pw
  int ph = pp / 20, pw = pp - ph * 20;
  const int* base = x + (((b * 3 + cin) * HW) + ph * 32) * HW + pw * 32;
  int r  = lane >> 1;                          // 0..31 (row in block)
  int c0 = (lane & 1) * 16;                    // 0 or 16 (col in block)
  const int4* p = (const int4*)(base + r * HW + c0);
  int4 v0 = p[0], v1 = p[1], v2 = p[2], v3 = p[3];
  int s = v0.x + v0.y + v0.z + v0.w + v1.x + v1.y + v1.z + v1.w
        + v2.x + v2.y + v2.z + v2.w + v3.x + v3.y + v3.z + v3.w;
  #pragma unroll
  for (int off = 32; off > 0; off >>= 1) s += __shfl_down(s, off);
  if (lane == 0) {
    int kout = (2 - cin) * 400 + pp;
    At[kout * 64 + b] = (double)s * (1.0 / 261120.0);  // / (255*1024)
  }
}

// ---------------- Kernel 2: fp64 GEMM, scalar A, reg dbuf, split-K ----------
// At: (1200,64) double   W: (1200,25200) float   Y: (2, 64, 25200) double
// blockIdx.y: bit0 = row group (rows [g*32,g*32+32)), bit1 = K chunk.
// Each of 4 waves: 8 batch rows (wave-uniform -> A reads are scalar loads),
// each lane one output column. Next k-step's 8 W values prefetched into a
// second register set before the FMA block. 1576 blocks x 4 waves =
// 6.15 waves/SIMD -> vmem/smem latency fully covered by FMA issue.
// Within a chunk, k ascending sequential fp64 fma; chunk partials are summed
// chunk0+chunk1 downstream (fp64 reorder noise ~1e-15, no decision flips).
__global__ __launch_bounds__(256) void gemm_kernel(const double* __restrict__ At,
                                                   const float* __restrict__ W,
                                                   double* __restrict__ Y) {
  int wave  = threadIdx.x >> 6;
  int lane  = threadIdx.x & 63;
  int grp   = blockIdx.y & 1;
  int chunk = blockIdx.y >> 1;
  int row0 = __builtin_amdgcn_readfirstlane((int)(grp * 32 + wave * 8));
  int n  = blockIdx.x * 64 + lane;
  int nl = n < NTOT ? n : NTOT - 1;            // clamp (no divergent load)
  const double* Ap = At + (size_t)chunk * KCH * 64 + row0;   // Ap[k*64 + i]
  const float*  Wp = W + (size_t)chunk * KCH * NTOT + nl;
  double acc[8];
  #pragma unroll
  for (int i = 0; i < 8; ++i) acc[i] = 0.0;
  float w[8];
  #pragma unroll
  for (int u = 0; u < 8; ++u) w[u] = Wp[(size_t)u * NTOT];
  #pragma unroll 1
  for (int k0 = 0; k0 < KCH; k0 += 8) {
    int kn = (k0 + 8 == KCH) ? 0 : k0 + 8;     // last prefetch wraps (unused)
    float wn[8];
    #pragma unroll
    for (int u = 0; u < 8; ++u) wn[u] = Wp[(size_t)(kn + u) * NTOT];
    #pragma unroll
    for (int u = 0; u < 8; ++u) {
      double wd = (double)w[u];
      #pragma unroll
      for (int i = 0; i < 8; ++i)
        acc[i] = fma(Ap[(size_t)(k0 + u) * 64 + i], wd, acc[i]);
    }
    #pragma unroll
    for (int u = 0; u < 8; ++u) w[u] = wn[u];
  }
  if (n < NTOT) {
    double* Yp = Y + ((size_t)chunk * BATCH + row0) * NTOT + n;
    #pragma unroll
    for (int i = 0; i < 8; ++i) Yp[(size_t)i * NTOT] = acc[i];
  }
}

// ---------------- Kernel 3a: per-query argmax over 80 classes ---------------
// One wave per (b,q). Sums the two K-chunk partials (fixed order), then
// shuffle max-reduce with tie -> smaller class index (numpy argmax order).
__global__ __launch_bounds__(256) void argmax_kernel(const double* __restrict__ Y,
                                                     double* __restrict__ sc,
                                                     int* __restrict__ cid) {
  int wave = threadIdx.x >> 6;
  int lane = threadIdx.x & 63;
  int task = blockIdx.x * 4 + wave;            // 0 .. 19199
  int b = task / NQ;
  int q = task - b * NQ;
  const double* y0 = Y + (size_t)b * NTOT + q * NCH;
  const double* y1 = y0 + (size_t)BATCH * NTOT;
  double best = y0[4 + lane] + y1[4 + lane];
  int    cls  = lane;
  if (lane < 16) {
    double v2 = y0[68 + lane] + y1[68 + lane];
    if (v2 > best) { best = v2; cls = 64 + lane; }   // strict > : lower idx wins ties
  }
  #pragma unroll
  for (int off = 32; off > 0; off >>= 1) {
    double ob = __shfl_down(best, off);
    int    oc = __shfl_down(cls, off);
    if (ob > best || (ob == best && oc < cls)) { best = ob; cls = oc; }
  }
  if (lane == 0) { sc[task] = best; cid[task] = cls; }
}

// ---------------- Kernel 3b: stable top-150 by rank selection ---------------
// One block per batch; scores in LDS; exact rank under (score desc, q asc);
// only the 150 winners touch global Y (both partials) for their boxes.
__global__ __launch_bounds__(256) void select_kernel(const double* __restrict__ Y,
                                                     const double* __restrict__ sc,
                                                     const int* __restrict__ cid,
                                                     float* __restrict__ out) {
  __shared__ double ssc[NQ];
  __shared__ int    scid[NQ];
  int b = blockIdx.x;
  int t = threadIdx.x;
  for (int q = t; q < NQ; q += 256) {
    ssc[q]  = sc[b * NQ + q];
    scid[q] = cid[b * NQ + q];
  }
  __syncthreads();
  for (int q = t; q < NQ; q += 256) {
    double s = ssc[q];
    int rank = 0;
    for (int j = 0; j < NQ; ++j) {
      double sj = ssc[j];
      rank += (sj > s) || (sj == s && j < q);
    }
    if (rank < KTOP) {
      const double* r0 = Y + (size_t)b * NTOT + q * NCH;
      const double* r1 = r0 + (size_t)BATCH * NTOT;
      float* o = out + ((size_t)b * KTOP + rank) * 6;
      o[0] = (float)(r0[0] + r1[0]);
      o[1] = (float)(r0[1] + r1[1]);
      o[2] = (float)(r0[2] + r1[2]);
      o[3] = (float)(r0[3] + r1[3]);
      o[4] = (float)s;
      o[5] = (float)scid[q];
    }
  }
}

extern "C" void kernel_launch(void* const* d_in, const int* in_sizes, int n_in,
                              void* d_out, int out_size, void* d_ws, size_t ws_size,
                              hipStream_t stream) {
  const int*   x = (const int*)d_in[0];
  const float* W = (const float*)d_in[1];
  double* At  = (double*)d_ws;
  double* Y   = (double*)((char*)d_ws + WS_Y);
  double* sc  = (double*)((char*)d_ws + WS_SC);
  int*    cid = (int*)((char*)d_ws + WS_CID);
  pool_kernel<<<dim3(19200), dim3(256), 0, stream>>>(x, At);
  gemm_kernel<<<dim3(394, 4), dim3(256), 0, stream>>>(At, W, Y);
  argmax_kernel<<<dim3(4800), dim3(256), 0, stream>>>(Y, sc, cid);
  select_kernel<<<dim3(64), dim3(256), 0, stream>>>(Y, sc, cid, (float*)d_out);
}